// Round 14
// baseline (56.739 us; speedup 1.0000x reference)
//
#include <hip/hip_runtime.h>

// LIF scan, B=65536 x L=400. Round 14: TIME-SPLIT rows -> 2 waves/SIMD.
// Evidence ledger: r10 best clean = 38.8us (FETCH 56/WRITE 104MB); r11-r13
// schedule variants 38-41us or racy -> per-wave scheduling exhausted. The
// remaining lever is parallelism: LIF's hard reset is a synchronizing
// nonlinearity — if the true trajectory (from v200) and a speculative one
// (from v=0) BOTH fire at step t, both reset to 0 and are bit-identical
// forever after. So:
//   wave0: rows' t=[0,200) exact from v=0 (true by construction).
//   wave1: rows' t=[200,400) speculative from v=0, bits to registers.
//   sync;  wave1 replays its prefix from true v200 (LDS) until first
//          joint-fire merge step, patching bits + (cnt,num) deltas. Exact.
//   sync;  both waves expand bits -> coalesced full-line nt f4 stores (r10).
// 131072 threads = 2048 waves = 2 waves/SIMD (vs 1 before): latency overlap
// + each wave's serial chain halved (200 steps).
// div20 = Markstein 2-fma correctly-rounded v/20 (validated r3-r12).

#define L_LEN 400
#define BIG 0x7fffffff

typedef float f4 __attribute__((ext_vector_type(4)));

__device__ __forceinline__ float div20(float v) {
    const float c = 0.05f;
    float q = v * c;
    float r = fmaf(-20.0f, q, v);
    return fmaf(r, c, q);
}

__global__ __launch_bounds__(128, 2) void lif_kernel(const float* __restrict__ I,
                                                     float* __restrict__ spikes,
                                                     float* __restrict__ hard_lat,
                                                     float* __restrict__ soft_lat) {
    __shared__ unsigned Aw[64][8];              // wave0's 7 bit-words (+pad)
    __shared__ float vend[64];                  // true v(200) per row
    __shared__ int numA_s[64], cntA_s[64], firstA_s[64];
    __shared__ unsigned bitsX[64][13];          // final packed row bits
    const int tid = threadIdx.x;
    const int j   = tid & 63;
    const int wid = tid >> 6;                   // 0: t<200, 1: t>=200 (spec)
    const int R0  = blockIdx.x * 64;
    const int row = R0 + j;
    const char* Ih = (const char*)I + (size_t)row * 1600 + wid * 800;

    f4 A[10], B[10];
    unsigned w[7] = {0, 0, 0, 0, 0, 0, 0};      // this half's 200 bits
    float v = 0.0f;
    int numH = 0, cntH = 0, firstH = BIG;       // half-LOCAL t (0..199)

    auto load40 = [&](int cb, f4* buf) {        // cb: literal byte offset
#pragma unroll
        for (int k = 0; k < 10; ++k)
            buf[k] = *reinterpret_cast<const f4*>(Ih + cb + k * 16);
    };
    auto scan40 = [&](int base, const f4* buf) {  // base: literal step offset
        unsigned long long hb = 0ull;
        int nl = 0;
#pragma unroll
        for (int k = 0; k < 10; ++k) {
            f4 x4 = buf[k];
#pragma unroll
            for (int m = 0; m < 4; ++m) {
                const int tl = k * 4 + m;
                // reference association: v = v + ((-v/20) + x)
                float d  = x4[m] - div20(v);
                float vn = v + d;
                bool fire = vn >= 1.0f;
                nl = fire ? nl + tl : nl;
                hb |= fire ? (1ull << tl) : 0ull;
                v = fire ? 0.0f : vn;
            }
        }
        int pc = __builtin_popcountll(hb);
        numH += nl + base * pc;
        cntH += pc;
        if (hb) firstH = min(firstH, base + (int)__builtin_ctzll(hb));
        const int wi = base >> 5, sh = base & 31;   // folds: base literal
        w[wi]     |= (unsigned)(hb << sh);
        w[wi + 1] |= (unsigned)(hb >> (32 - sh));
    };

    // 5 chunks x 40 steps, static double-buffer (r12 lesson: no runtime select)
    load40(0, A);
    load40(160, B);
    scan40(0, A);    load40(320, A);
    scan40(40, B);   load40(480, B);
    scan40(80, A);   load40(640, A);
    scan40(120, B);
    scan40(160, A);

    if (wid == 0) {
#pragma unroll
        for (int k = 0; k < 7; ++k) Aw[j][k] = w[k];
        vend[j] = v;
        numA_s[j] = numH; cntA_s[j] = cntH; firstA_s[j] = firstH;
    }
    __syncthreads();

    if (wid == 1) {
        // ---- fixup: replay prefix from true v200 until joint-fire merge ----
        float vt = vend[j];
        bool merged = false;
        int dnum = 0, dcnt = 0;
#pragma unroll
        for (int wi = 0; wi < 7; ++wi) {        // 32-step word epochs, static
            if (!__any(!merged)) break;
            const int nb = (wi < 6) ? 32 : 8;
            f4 xb[8];
#pragma unroll
            for (int k = 0; k < 8; ++k)
                if (k * 4 < nb)
                    xb[k] = *reinterpret_cast<const f4*>(Ih + wi * 128 + k * 16);
            unsigned uw = w[wi];
#pragma unroll
            for (int b = 0; b < 32; ++b) {
                if (b >= nb) break;             // folds (nb literal per epoch)
                if (!merged) {
                    const int t = wi * 32 + b;  // local t in [0,200)
                    float d  = xb[b >> 2][b & 3] - div20(vt);
                    float vn = vt + d;
                    bool ft = vn >= 1.0f;
                    int sb = (int)((uw >> b) & 1u);
                    int df = (int)ft - sb;
                    dcnt += df;
                    dnum += t * df;
                    uw = (uw & ~(1u << b)) | (ft ? (1u << b) : 0u);
                    merged = ft && (sb != 0);   // both fire -> states merge
                    vt = ft ? 0.0f : vn;
                }
            }
            w[wi] = uw;
        }

        int cntB  = cntH + dcnt;
        int numBl = numH + dnum;
        int fB = -1;                            // first set bit of final words
#pragma unroll
        for (int wi = 6; wi >= 0; --wi)
            if (w[wi]) fB = wi * 32 + (int)__builtin_ctz(w[wi]);

        int numA = numA_s[j], cntA = cntA_s[j], firstA = firstA_s[j];
        int hard = (firstA != BIG) ? firstA : (fB >= 0 ? 200 + fB : 0);
        int cntT = cntA + cntB;
        int numT = numA + numBl + 200 * cntB;
        hard_lat[row] = (float)hard;
        soft_lat[row] = (float)numT / ((float)cntT + 1e-6f);

        // ---- assemble 13 row words: A(0..199) then B at bit offset 200 ----
        unsigned ww[13];
#pragma unroll
        for (int k = 0; k < 7; ++k) ww[k] = Aw[j][k];   // ww6 has bits 0..7
#pragma unroll
        for (int k = 0; k < 7; ++k) {
            ww[6 + k] |= (w[k] & 0xFFFFFFu) << 8;
            if (6 + k + 1 < 13) ww[6 + k + 1] = (w[k] >> 24);
        }
#pragma unroll
        for (int k = 0; k < 13; ++k) bitsX[j][k] = ww[k];
    }
    __syncthreads();

    // ---- expand: both waves, fully-coalesced full-line nt stores (r10) ----
    char* Sb = (char*)spikes + (size_t)R0 * 1600;
#pragma unroll
    for (int i = 0; i < 50; ++i) {
        int flat = i * 128 + tid;               // 0..6399 = r*100 + k
        int r = flat / 100;
        int k = flat - r * 100;
        unsigned u = bitsX[r][k >> 3];
        int sh = (k & 7) * 4;
        f4 s;
        s.x = (float)((u >> (sh + 0)) & 1u);
        s.y = (float)((u >> (sh + 1)) & 1u);
        s.z = (float)((u >> (sh + 2)) & 1u);
        s.w = (float)((u >> (sh + 3)) & 1u);
        __builtin_nontemporal_store(s, reinterpret_cast<f4*>(Sb + (size_t)flat * 16));
    }
}

extern "C" void kernel_launch(void* const* d_in, const int* in_sizes, int n_in,
                              void* d_out, int out_size, void* d_ws, size_t ws_size,
                              hipStream_t stream) {
    const float* I = (const float*)d_in[0];
    int B = in_sizes[0] / L_LEN;  // 65536

    float* spk = (float*)d_out;
    float* hard = spk + (size_t)B * L_LEN;
    float* soft = hard + B;

    dim3 block(128);
    dim3 grid(B / 64);  // 1024 blocks x 2 waves = 2 waves/SIMD
    hipLaunchKernelGGL(lif_kernel, grid, block, 0, stream, I, spk, hard, soft);
}

// Round 15
// 38.195 us; speedup vs baseline: 1.4855x; 1.4855x over previous
//
#include <hip/hip_runtime.h>

// LIF scan, B=65536 x L=400. Round 15: r10 structure, HALF-WIDTH blocks.
// Evidence ledger:
//   r10 best: 38.8us, FETCH 56/WRITE 104MB clean, nt full-line stores.
//   r11/r12 schedule permutations: 38.8-42 -> compiler already optimal.
//   r13 DMA/vmcnt: racy. r14 time-split: +fixup serial chain, 56.7us.
//   Diagnosis: fabric 209MB/38.8us = 5.4 TB/s = 86% of 6.29 copy ceiling;
//   grid caps residency at 1 wave/SIMD -> each SIMD's memory queue empties
//   during its lone wave's 2240cy scan chain. No schedule fixes that.
// This round: ROWS=32 per block (same code, half width), grid=2048
//   -> 8 blocks/CU = 2 waves/SIMD. Loads/stores still 1KB-contiguous per
//   instruction (10 instr/chunk). Scan predicated to lanes 0-31 (VALU is 14%
//   busy - the waste is free). Two resident waves/SIMD interleave: one wave's
//   chain covers the other's bursts. No barriers, no sync changes.
// div20 = Markstein 2-fma correctly-rounded v/20 (validated r3-r14).

#define L_LEN 400
#define TC 80
#define NC 5
#define F4C 20
#define ROWS 32
#define F4T 10               // load/store instrs per chunk = ROWS*F4C/64
#define PITCHF 96
#define BIG 0x7fffffff

typedef float f4 __attribute__((ext_vector_type(4)));

__device__ __forceinline__ float div20(float v) {
    const float c = 0.05f;
    float q = v * c;
    float r = fmaf(-20.0f, q, v);
    return fmaf(r, c, q);
}

__global__ __launch_bounds__(64) void lif_kernel(const float* __restrict__ I,
                                                 float* __restrict__ spikes,
                                                 float* __restrict__ hard_lat,
                                                 float* __restrict__ soft_lat) {
    __shared__ float lds_in[ROWS * PITCHF];   // 12288 B
    __shared__ unsigned bitsb[ROWS * 3];      // 384 B
    const int j = threadIdx.x;
    const int R0 = blockIdx.x * ROWS;
    const char* Ib = (const char*)I + (size_t)R0 * 1600;
    char* Sb = (char*)spikes + (size_t)R0 * 1600;

    // coalesced walker: flat = i*64+j in [0, ROWS*F4C), r = flat/20, k = flat%20
    const int r0 = j / 20;
    const int k0 = j - r0 * 20;

    f4 regs[F4T];

    auto load_coal = [&](int c, f4* rg) {
        int r = r0, k = k0;
        int off = r * 1600 + k * 16 + c * 320;
#pragma unroll
        for (int i = 0; i < F4T; ++i) {
            rg[i] = *reinterpret_cast<const f4*>(Ib + off);
            int kn = k + 4; bool cr = kn >= 20;
            k = cr ? kn - 20 : kn;
            r += cr ? 4 : 3;
            off += cr ? 6144 : 4864;
        }
    };

    auto write_lds = [&](const f4* rg) {
        int r = r0, k = k0;
#pragma unroll
        for (int i = 0; i < F4T; ++i) {
            *reinterpret_cast<f4*>(&lds_in[r * PITCHF + ((k ^ (r & 7)) << 2)]) = rg[i];
            int kn = k + 4; bool cr = kn >= 20;
            k = cr ? kn - 20 : kn;
            r += cr ? 4 : 3;
        }
    };

    load_coal(0, regs);
    write_lds(regs);

    float v = 0.0f;
    int num = 0, cnt = 0, first = BIG;
    float* myrow = &lds_in[j * PITCHF];       // valid for j < ROWS
    const int jx = j & 7;

#pragma unroll 1
    for (int c = 0; c < NC; ++c) {
        if (c + 1 < NC) load_coal(c + 1, regs);   // prefetch under the scan

        if (j < ROWS) {
            // ---- scan chunk c from LDS (swizzled b128 reads, 1 lane/bank) ----
            unsigned b0 = 0, b1 = 0, b2 = 0;
            int numL = 0;
#pragma unroll
            for (int k = 0; k < F4C; ++k) {
                f4 x4 = *reinterpret_cast<const f4*>(&myrow[((k ^ jx) << 2)]);
#pragma unroll
                for (int m = 0; m < 4; ++m) {
                    const int tl = k * 4 + m;
                    float x = x4[m];
                    // reference association: v = v + ((-v/20) + x)
                    float d  = x - div20(v);
                    float vn = v + d;
                    bool fire = vn >= 1.0f;
                    numL = fire ? numL + tl : numL;
                    if (tl < 32)      b0 |= fire ? (1u << tl) : 0u;
                    else if (tl < 64) b1 |= fire ? (1u << (tl - 32)) : 0u;
                    else              b2 |= fire ? (1u << (tl - 64)) : 0u;
                    v = fire ? 0.0f : vn;
                }
            }
            int cntC = __builtin_popcount(b0) + __builtin_popcount(b1) +
                       __builtin_popcount(b2);
            int fl = b0 ? __builtin_ctz(b0)
                   : (b1 ? 32 + __builtin_ctz(b1)
                   : (b2 ? 64 + __builtin_ctz(b2) : -1));
            int cbase = c * TC;
            num += numL + cbase * cntC;
            cnt += cntC;
            first = min(first, fl >= 0 ? cbase + fl : BIG);

            bitsb[j * 3 + 0] = b0;
            bitsb[j * 3 + 1] = b1;
            bitsb[j * 3 + 2] = b2;
        }
        // single wave: exec-mask reconverges; DS ops in-order, no barrier.

        // ---- expand: all 64 lanes, coalesced full-line nt stores ----
        {
            int r = r0, k = k0;
            int off = r * 1600 + k * 16 + c * 320;
#pragma unroll
            for (int i = 0; i < F4T; ++i) {
                unsigned w = bitsb[r * 3 + (k >> 3)];
                int sh = (k & 7) * 4;
                f4 s;
                s.x = (float)((w >> (sh + 0)) & 1u);
                s.y = (float)((w >> (sh + 1)) & 1u);
                s.z = (float)((w >> (sh + 2)) & 1u);
                s.w = (float)((w >> (sh + 3)) & 1u);
                __builtin_nontemporal_store(s, reinterpret_cast<f4*>(Sb + off));
                int kn = k + 4; bool cr = kn >= 20;
                k = cr ? kn - 20 : kn;
                r += cr ? 4 : 3;
                off += cr ? 6144 : 4864;
            }
        }

        if (c + 1 < NC) write_lds(regs);
    }

    if (j < ROWS) {
        const int row = R0 + j;
        hard_lat[row] = (float)(first == BIG ? 0 : first);
        soft_lat[row] = (float)num / ((float)cnt + 1e-6f);
    }
}

extern "C" void kernel_launch(void* const* d_in, const int* in_sizes, int n_in,
                              void* d_out, int out_size, void* d_ws, size_t ws_size,
                              hipStream_t stream) {
    const float* I = (const float*)d_in[0];
    int B = in_sizes[0] / L_LEN;  // 65536

    float* spk = (float*)d_out;
    float* hard = spk + (size_t)B * L_LEN;
    float* soft = hard + B;

    dim3 block(64);
    dim3 grid(B / ROWS);  // 2048 blocks -> 8 blocks/CU = 2 waves/SIMD
    hipLaunchKernelGGL(lif_kernel, grid, block, 0, stream, I, spk, hard, soft);
}